// Round 1
// baseline (521.077 us; speedup 1.0000x reference)
//
#include <hip/hip_runtime.h>
#include <stdint.h>

#define T_LEN 2048
#define BATCH 64
#define I_DIM 256
#define H_DIM 256
#define N3    768                  // 3*H
#define M_ROWS (T_LEN*BATCH)       // 131072
#define L2E 1.4426950408889634f

typedef __attribute__((ext_vector_type(4))) float  f32x4;
typedef __attribute__((ext_vector_type(4))) unsigned short u16x4;
typedef __attribute__((ext_vector_type(4))) unsigned int   u32x4;
typedef __attribute__((ext_vector_type(8))) __bf16 bf16x8;

__device__ __forceinline__ unsigned short f2bf_rne(float f) {
    uint32_t u = __float_as_uint(f);
    u += 0x7FFFu + ((u >> 16) & 1u);
    return (unsigned short)(u >> 16);
}
__device__ __forceinline__ float bf2f(unsigned short b) {
    return __uint_as_float(((uint32_t)b) << 16);
}

// ---------------------------------------------------------------------------
// Kernel 0: convert W_ih [768,256] f32 -> bf16 hi/lo, with the gate scaling
// (-log2e for r,z rows; -2*log2e for n rows) baked in so the scan kernel's
// critical path needs no extra multiplies.
// ---------------------------------------------------------------------------
__global__ void convert_w(const float* __restrict__ W,
                          unsigned short* __restrict__ Whi,
                          unsigned short* __restrict__ Wlo) {
    int idx = blockIdx.x * 256 + threadIdx.x;       // 768*256 total
    int row = idx >> 8;
    float scale = (row < 2*H_DIM) ? -L2E : -2.0f*L2E;
    float v = W[idx] * scale;
    unsigned short hi = f2bf_rne(v);
    Whi[idx] = hi;
    Wlo[idx] = f2bf_rne(v - bf2f(hi));
}

// ---------------------------------------------------------------------------
// Kernel 1: gx[M,768] = X[M,256] * W^T  via bf16x3 MFMA (hi*hi+hi*lo+lo*hi).
// BM=128, BN=128, BK=64, 256 threads (4 waves, 2x2), XOR-swizzled LDS.
// ---------------------------------------------------------------------------
#define BM 128
#define BN 128
#define BK 64

__device__ __forceinline__ int lds_swz(int row, int kbyte) {
    // row stride 128B (64 bf16); XOR 16B-unit index with row&7 -> conflict-free b128 reads
    return row * 128 + (kbyte ^ ((row & 7) << 4));
}

__global__ __launch_bounds__(256, 2) void gemm_gx(
        const float* __restrict__ X,
        const unsigned short* __restrict__ Whi,
        const unsigned short* __restrict__ Wlo,
        float* __restrict__ gx) {
    __shared__ unsigned short sAhi[BM*BK], sAlo[BM*BK], sBhi[BN*BK], sBlo[BN*BK];

    // XCD-chunked swizzle: 6144 blocks, 8 XCDs -> each XCD gets 128 M-panels x 6 N
    int wg   = blockIdx.x;
    int orig = (wg & 7) * 768 + (wg >> 3);
    int mblk = orig / 6, nblk = orig - mblk * 6;
    int m0 = mblk * BM, n0 = nblk * BN;

    int tid  = threadIdx.x;
    int lane = tid & 63, wid = tid >> 6;
    int wm = wid >> 1, wn = wid & 1;

    int acol = tid & 15, arow = tid >> 4;   // A staging: float4 granularity
    int bcol = tid & 7,  brow = tid >> 3;   // B staging: 16B (8 bf16) granularity

    f32x4 acc[4][4] = {};

    for (int kb = 0; kb < 4; ++kb) {
        // ---- global loads into regs (issued before the barrier: overlap) ----
        f32x4 ra[8];
        u32x4 rbh[4], rbl[4];
        #pragma unroll
        for (int p = 0; p < 8; ++p) {
            int row = p*16 + arow;
            ra[p] = *(const f32x4*)(X + (size_t)(m0+row)*I_DIM + kb*BK + acol*4);
        }
        #pragma unroll
        for (int p = 0; p < 4; ++p) {
            int row = p*32 + brow;
            rbh[p] = *(const u32x4*)(Whi + (size_t)(n0+row)*I_DIM + kb*BK + bcol*8);
            rbl[p] = *(const u32x4*)(Wlo + (size_t)(n0+row)*I_DIM + kb*BK + bcol*8);
        }
        __syncthreads();   // prior iteration's LDS reads complete
        #pragma unroll
        for (int p = 0; p < 8; ++p) {
            int row = p*16 + arow;
            u16x4 hi, lo;
            #pragma unroll
            for (int e = 0; e < 4; ++e) {
                float v = ra[p][e];
                unsigned short hb = f2bf_rne(v);
                hi[e] = hb;
                lo[e] = f2bf_rne(v - bf2f(hb));
            }
            int off = lds_swz(row, acol*8);
            *(u16x4*)((char*)sAhi + off) = hi;
            *(u16x4*)((char*)sAlo + off) = lo;
        }
        #pragma unroll
        for (int p = 0; p < 4; ++p) {
            int row = p*32 + brow;
            int off = lds_swz(row, bcol*16);
            *(u32x4*)((char*)sBhi + off) = rbh[p];
            *(u32x4*)((char*)sBlo + off) = rbl[p];
        }
        __syncthreads();
        // ---- MFMA over the two K=32 sub-steps ----
        #pragma unroll
        for (int kk = 0; kk < 2; ++kk) {
            bf16x8 ah[4], al[4], bh[4], bl[4];
            #pragma unroll
            for (int mi = 0; mi < 4; ++mi) {
                int row = wm*64 + mi*16 + (lane & 15);
                int off = lds_swz(row, kk*64 + (lane >> 4)*16);
                ah[mi] = *(const bf16x8*)((const char*)sAhi + off);
                al[mi] = *(const bf16x8*)((const char*)sAlo + off);
            }
            #pragma unroll
            for (int ni = 0; ni < 4; ++ni) {
                int row = wn*64 + ni*16 + (lane & 15);
                int off = lds_swz(row, kk*64 + (lane >> 4)*16);
                bh[ni] = *(const bf16x8*)((const char*)sBhi + off);
                bl[ni] = *(const bf16x8*)((const char*)sBlo + off);
            }
            #pragma unroll
            for (int mi = 0; mi < 4; ++mi)
              #pragma unroll
              for (int ni = 0; ni < 4; ++ni) {
                acc[mi][ni] = __builtin_amdgcn_mfma_f32_16x16x32_bf16(ah[mi], bh[ni], acc[mi][ni], 0,0,0);
                acc[mi][ni] = __builtin_amdgcn_mfma_f32_16x16x32_bf16(ah[mi], bl[ni], acc[mi][ni], 0,0,0);
                acc[mi][ni] = __builtin_amdgcn_mfma_f32_16x16x32_bf16(al[mi], bh[ni], acc[mi][ni], 0,0,0);
              }
        }
    }
    // ---- epilogue: C/D layout col=lane&15, row=(lane>>4)*4+j ----
    #pragma unroll
    for (int mi = 0; mi < 4; ++mi) {
        int rbase = m0 + wm*64 + mi*16 + (lane >> 4)*4;
        #pragma unroll
        for (int ni = 0; ni < 4; ++ni) {
            int col = n0 + wn*64 + ni*16 + (lane & 15);
            #pragma unroll
            for (int j = 0; j < 4; ++j)
                gx[(size_t)(rbase + j)*N3 + col] = acc[mi][ni][j];
        }
    }
}

// ---------------------------------------------------------------------------
// Kernel 2: diagonal-GRU scan. 16384 independent chains (B*H), one lane each.
// gx arrives pre-scaled by -log2e (r,z) / -2log2e (n), so each gate is one
// fma -> v_exp_f32 -> add -> v_rcp_f32. 16-step register prefetch ring.
// ---------------------------------------------------------------------------
__global__ __launch_bounds__(64) void indgru_scan(
        const float* __restrict__ gx, const float* __restrict__ bih,
        const float* __restrict__ bhh, const float* __restrict__ whh,
        float* __restrict__ out) {
    int lane = threadIdx.x;
    int b = blockIdx.x >> 2;
    int h = (blockIdx.x & 3) * 64 + lane;

    float whr = -L2E  * whh[h];
    float whz = -L2E  * whh[H_DIM + h];
    float whn = -2.0f*L2E * whh[2*H_DIM + h];
    float cr  = -L2E  * (bih[h] + bhh[h]);
    float cz  = -L2E  * (bih[H_DIM+h] + bhh[H_DIM+h]);
    float cn  = -2.0f*L2E * bih[2*H_DIM+h];
    float bhn = -2.0f*L2E * bhh[2*H_DIM+h];

    const size_t sg = (size_t)BATCH * N3;     // gx stride per t
    const size_t so = (size_t)BATCH * H_DIM;  // out stride per t
    const float* pr = gx + (size_t)b*N3 + h;
    float* po = out + (size_t)b*H_DIM + h;

    float fr[16], fz[16], fn[16];
    {
        const float* p = pr;
        #pragma unroll
        for (int i = 0; i < 16; ++i) {
            fr[i] = p[0]; fz[i] = p[H_DIM]; fn[i] = p[2*H_DIM];
            p += sg;
        }
    }
    const float* prp = pr + 16*sg;   // prefetch cursor (t+16)
    float hv = 0.f;

    for (int tb = 0; tb < T_LEN/16 - 1; ++tb) {
        #pragma unroll
        for (int j = 0; j < 16; ++j) {
            float ur = fr[j] + cr, uz = fz[j] + cz, un = fn[j] + cn;
            fr[j] = prp[0]; fz[j] = prp[H_DIM]; fn[j] = prp[2*H_DIM];
            prp += sg;
            float er = __builtin_amdgcn_exp2f(fmaf(whr, hv, ur));
            float r  = __builtin_amdgcn_rcpf(1.f + er);
            float ez = __builtin_amdgcn_exp2f(fmaf(whz, hv, uz));
            float z  = __builtin_amdgcn_rcpf(1.f + ez);
            float mn = fmaf(whn, hv, bhn);
            float en = __builtin_amdgcn_exp2f(fmaf(r, mn, un));
            float q  = __builtin_amdgcn_rcpf(1.f + en);
            float hp1 = hv + 1.f;
            hv = fmaf(z, fmaf(-2.f, q, hp1), fmaf(2.f, q, -1.f));
            *po = hv; po += so;
        }
    }
    #pragma unroll
    for (int j = 0; j < 16; ++j) {           // last 16 steps, no prefetch
        float ur = fr[j] + cr, uz = fz[j] + cz, un = fn[j] + cn;
        float er = __builtin_amdgcn_exp2f(fmaf(whr, hv, ur));
        float r  = __builtin_amdgcn_rcpf(1.f + er);
        float ez = __builtin_amdgcn_exp2f(fmaf(whz, hv, uz));
        float z  = __builtin_amdgcn_rcpf(1.f + ez);
        float mn = fmaf(whn, hv, bhn);
        float en = __builtin_amdgcn_exp2f(fmaf(r, mn, un));
        float q  = __builtin_amdgcn_rcpf(1.f + en);
        float hp1 = hv + 1.f;
        hv = fmaf(z, fmaf(-2.f, q, hp1), fmaf(2.f, q, -1.f));
        *po = hv; po += so;
    }
    out[(size_t)T_LEN * so + (size_t)b*H_DIM + h] = hv;   // h_n
}

// ---------------------------------------------------------------------------
extern "C" void kernel_launch(void* const* d_in, const int* in_sizes, int n_in,
                              void* d_out, int out_size, void* d_ws, size_t ws_size,
                              hipStream_t stream) {
    const float* x   = (const float*)d_in[0];
    const float* Wih = (const float*)d_in[1];
    const float* bih = (const float*)d_in[2];
    const float* bhh = (const float*)d_in[3];
    const float* whh = (const float*)d_in[4];
    float* out = (float*)d_out;

    char* ws = (char*)d_ws;
    float* gxbuf = (float*)ws;                                  // 384 MiB
    unsigned short* Whi = (unsigned short*)(ws + (size_t)M_ROWS*N3*sizeof(float));
    unsigned short* Wlo = Whi + (size_t)N3*I_DIM;

    convert_w<<<(N3*I_DIM)/256, 256, 0, stream>>>(Wih, Whi, Wlo);
    gemm_gx<<<(M_ROWS/BM)*(N3/BN), 256, 0, stream>>>(x, Whi, Wlo, gxbuf);
    indgru_scan<<<BATCH*(H_DIM/64), 64, 0, stream>>>(gxbuf, bih, bhh, whh, out);
}